// Round 8
// baseline (357.937 us; speedup 1.0000x reference)
//
#include <hip/hip_runtime.h>
#include <math.h>
#include <float.h>

#define NROWS 131072
#define SDIM 64
#define HDIM 128
#define KCODES 512
#define ADIM 8

// ===========================================================================
// prep: eT[j][c] = emb[c][j]  (256 KB), j-major so VQ staging reads are
// coalesced rows of codes.
// ===========================================================================
__global__ void prep_e_kernel(const float* __restrict__ emb, float* __restrict__ eT) {
    int g = blockIdx.x * 256 + threadIdx.x;        // 0..16383
    int c = g >> 5, j4 = g & 31;
    float4 v = ((const float4*)emb)[(size_t)c * 32 + j4];
    eT[(size_t)(4 * j4 + 0) * KCODES + c] = v.x;
    eT[(size_t)(4 * j4 + 1) * KCODES + c] = v.y;
    eT[(size_t)(4 * j4 + 2) * KCODES + c] = v.z;
    eT[(size_t)(4 * j4 + 3) * KCODES + c] = v.w;
}

// ee[k] = sum_j emb[k][j]^2 — exact FP chain (absmax 0.0)
__global__ void ee_kernel(const float* __restrict__ emb, float* __restrict__ ee) {
    int k = blockIdx.x * blockDim.x + threadIdx.x;
    if (k >= KCODES) return;
    const float* e = emb + k * HDIM;
    float a0 = 0.f, a1 = 0.f, a2 = 0.f, a3 = 0.f;
#pragma unroll
    for (int j = 0; j < HDIM; j += 4) {
        a0 = fmaf(e[j + 0], e[j + 0], a0);
        a1 = fmaf(e[j + 1], e[j + 1], a1);
        a2 = fmaf(e[j + 2], e[j + 2], a2);
        a3 = fmaf(e[j + 3], e[j + 3], a3);
    }
    ee[k] = (a0 + a1) + (a2 + a3);
}

// ===========================================================================
// MLP (round-5 structure, kept): 64-row blocks, shared [128][65] region,
// launch_bounds(256,3). Lane l owns row l; wave wu owns cols [wu*32,+32).
// Chains exact (s-asc, t-asc); vv grouping ((p0+p1)+p2)+p3 — bit-exact.
// ===========================================================================
__global__ __launch_bounds__(256, 3) void mlp_kernel(
    const float* __restrict__ in,
    const float* __restrict__ W1, const float* __restrict__ b1,
    const float* __restrict__ Wh, const float* __restrict__ bh,
    float* __restrict__ x2t, float* __restrict__ vvs, int rstride)
{
    __shared__ float buf[8320];                   // [128][65] = 33.3 KB
    const int tid = threadIdx.x;
    const int wu = __builtin_amdgcn_readfirstlane(tid >> 6);
    const int l = tid & 63;
    const int brow = blockIdx.x * 64;
    const int c0 = wu * 32;

    {   // stage in^T: buf[s][r] = in[brow+r][s], [64][65]
        const float4* src = (const float4*)(in + (size_t)brow * SDIM);
#pragma unroll
        for (int u = 0; u < 4; ++u) {
            int idx = tid + 256 * u;              // 0..1023
            int r = idx >> 4, s4 = idx & 15;
            float4 v = src[idx];
            buf[(4 * s4 + 0) * 65 + r] = v.x;
            buf[(4 * s4 + 1) * 65 + r] = v.y;
            buf[(4 * s4 + 2) * 65 + r] = v.z;
            buf[(4 * s4 + 3) * 65 + r] = v.w;
        }
    }
    __syncthreads();

    float acc[32];
#pragma unroll
    for (int cc = 0; cc < 32; ++cc) acc[cc] = b1[c0 + cc];
#pragma unroll 4
    for (int s = 0; s < SDIM; ++s) {              // s ascending: exact chain
        float xa = buf[s * 65 + l];
        const float* wr = W1 + s * HDIM + c0;     // uniform -> s_load
#pragma unroll
        for (int cc = 0; cc < 32; ++cc) acc[cc] = fmaf(xa, wr[cc], acc[cc]);
    }
    __syncthreads();                              // in-buf reads done; reuse
#pragma unroll
    for (int cc = 0; cc < 32; ++cc)
        buf[(c0 + cc) * 65 + l] = fmaxf(acc[cc], 0.f);
    __syncthreads();

#pragma unroll
    for (int cc = 0; cc < 32; ++cc) acc[cc] = bh[c0 + cc];
#pragma unroll 4
    for (int t = 0; t < HDIM; ++t) {              // t ascending: exact chain
        float xa = buf[t * 65 + l];
        const float* wr = Wh + t * HDIM + c0;     // uniform -> s_load
#pragma unroll
        for (int cc = 0; cc < 32; ++cc) acc[cc] = fmaf(xa, wr[cc], acc[cc]);
    }
    float pa = 0.f;
#pragma unroll
    for (int cc = 0; cc < 32; ++cc) {
        float a = fmaxf(acc[cc], 0.f);
        x2t[(size_t)(c0 + cc) * rstride + brow + l] = a;
        pa = fmaf(a, a, pa);
    }
    __syncthreads();                              // x1 reads done; reuse buf
    buf[wu * 64 + l] = pa;
    __syncthreads();
    if (tid < 64) {
        float vv = ((buf[tid] + buf[64 + tid]) + buf[128 + tid]) + buf[192 + tid];
        vvs[brow + tid] = vv;
    }
}

// ===========================================================================
// VQ — Round 8: barrier-free loop (R7) + two fixes from the R7 profile:
// (a) x-read bank conflicts (4.46M cycles: 8*tr7 mod 32 hits only 4 bank-
//     groups twice) -> store row r at slot r + 4*(r>>5); read at
//     8*tr7 + 4*(tr7>>2) -> {0,8,16,24,4,12,20,28} mod 32: conflict-free.
// (b) e-global latency exposed between FMA blocks -> T14 register prefetch:
//     chunk kc+1's 8 float4 loads issue right after chunk kc's ds_writes
//     (sched_barrier-pinned), retire under kc's 2048-FMA block; ds_write at
//     next chunk top. Now affordable: VGPR 104 + 32 << 256 cap at the
//     LDS-capped 2 waves/SIMD (R3's failure was the 128-reg budget).
// WAR (write over chunk kc-1's read slots) is same-wave in-order LDS: safe.
// Values/chains identical (regs passthrough; x relocation is a slot
// permutation) — bit-exact. Heads inline (exact chain).
// ===========================================================================
#define VV8(ri) ((ri)==0?vv0.x:(ri)==1?vv0.y:(ri)==2?vv0.z:(ri)==3?vv0.w: \
                 (ri)==4?vv1.x:(ri)==5?vv1.y:(ri)==6?vv1.z:vv1.w)

__global__ __launch_bounds__(256, 1) void vq_kernel(
    const float* __restrict__ x2t, const float* __restrict__ eT,
    const float* __restrict__ eew, const float* __restrict__ vvs,
    const float* __restrict__ emb,
    const float* __restrict__ Wa, const float* __restrict__ ba,
    const float* __restrict__ Wv, const float* __restrict__ bv,
    float* __restrict__ out, int rstride)
{
    __shared__ float smem[19456];                 // 77824 B
    float* xB  = smem;                            // [128][68] = 8704
    float* eB  = smem + 8704;                     // 4 x wave-private [16][160]
    float* eeL = smem + 18944;                    // [512]
    const int tid  = threadIdx.x;
    const int lane = tid & 63;
    const int wv   = __builtin_amdgcn_readfirstlane(tid >> 6);
    const int tr7  = lane & 7;                    // rows 8*tr7 .. +7
    const int tcw  = lane >> 3;                   // 0..7: 16-code group
    const int brow = blockIdx.x * 64;
    const int wcode = wv * 128;

    eeL[tid]       = eew[tid];
    eeL[tid + 256] = eew[tid + 256];

    {   // stage x once for full K; row r -> slot r + 4*(r>>5) (bank swizzle)
#pragma unroll
        for (int u = 0; u < 8; ++u) {
            int idx = tid + 256 * u;              // 0..2047
            int kk = idx >> 4, rq = idx & 15;     // rows 4rq..4rq+3
            float4 xv = *(const float4*)(x2t + (size_t)kk * rstride + brow + 4 * rq);
            *(float4*)(xB + kk * 68 + 4 * rq + 4 * (rq >> 3)) = xv;
        }
    }
    __syncthreads();                              // the ONLY pre-reduction barrier

    float4 vv0 = *(const float4*)(vvs + brow + 8 * tr7);
    float4 vv1 = *(const float4*)(vvs + brow + 8 * tr7 + 4);

    float acc[8][16];
#pragma unroll
    for (int ri = 0; ri < 8; ++ri)
#pragma unroll
        for (int ci = 0; ci < 16; ++ci) acc[ri][ci] = 0.f;

    float* eW = eB + wv * 2560;                   // this wave's [16][160]
    const int kb = lane >> 5;                     // 0/1
    const int rq = lane & 31;                     // code quad
    const float* eSrc = eT + (size_t)wcode + 4 * rq + (size_t)kb * KCODES;
    float* eDst = eW + kb * 160 + 4 * rq + 4 * (rq >> 2);

    float4 se0, se1, se2, se3, se4, se5, se6, se7;

#define LOADE(kc_) do {                                                        \
    const float* p_ = eSrc + (size_t)((kc_) * 16) * KCODES;                    \
    se0 = *(const float4*)(p_);                                                \
    se1 = *(const float4*)(p_ + 2  * KCODES);                                  \
    se2 = *(const float4*)(p_ + 4  * KCODES);                                  \
    se3 = *(const float4*)(p_ + 6  * KCODES);                                  \
    se4 = *(const float4*)(p_ + 8  * KCODES);                                  \
    se5 = *(const float4*)(p_ + 10 * KCODES);                                  \
    se6 = *(const float4*)(p_ + 12 * KCODES);                                  \
    se7 = *(const float4*)(p_ + 14 * KCODES);                                  \
} while (0)

#define WRITEE() do {                                                          \
    *(float4*)(eDst + 0    ) = se0;                                            \
    *(float4*)(eDst + 320  ) = se1;                                            \
    *(float4*)(eDst + 640  ) = se2;                                            \
    *(float4*)(eDst + 960  ) = se3;                                            \
    *(float4*)(eDst + 1280 ) = se4;                                            \
    *(float4*)(eDst + 1600 ) = se5;                                            \
    *(float4*)(eDst + 1920 ) = se6;                                            \
    *(float4*)(eDst + 2240 ) = se7;                                            \
} while (0)

#define FMA16(ri, xv) \
    acc[ri][0]  = fmaf(xv, e0.x, acc[ri][0]);  acc[ri][1]  = fmaf(xv, e0.y, acc[ri][1]);  \
    acc[ri][2]  = fmaf(xv, e0.z, acc[ri][2]);  acc[ri][3]  = fmaf(xv, e0.w, acc[ri][3]);  \
    acc[ri][4]  = fmaf(xv, e1.x, acc[ri][4]);  acc[ri][5]  = fmaf(xv, e1.y, acc[ri][5]);  \
    acc[ri][6]  = fmaf(xv, e1.z, acc[ri][6]);  acc[ri][7]  = fmaf(xv, e1.w, acc[ri][7]);  \
    acc[ri][8]  = fmaf(xv, e2.x, acc[ri][8]);  acc[ri][9]  = fmaf(xv, e2.y, acc[ri][9]);  \
    acc[ri][10] = fmaf(xv, e2.z, acc[ri][10]); acc[ri][11] = fmaf(xv, e2.w, acc[ri][11]); \
    acc[ri][12] = fmaf(xv, e3.x, acc[ri][12]); acc[ri][13] = fmaf(xv, e3.y, acc[ri][13]); \
    acc[ri][14] = fmaf(xv, e3.z, acc[ri][14]); acc[ri][15] = fmaf(xv, e3.w, acc[ri][15]);

    LOADE(0);                                     // prologue prefetch

    for (int kc = 0; kc < 8; ++kc) {              // 8 chunks x 16 k; NO barriers
        WRITEE();                                 // ds_write prefetched chunk
        if (kc < 7) LOADE(kc + 1);                // next chunk: retires under FMAs
        __builtin_amdgcn_sched_barrier(0);        // pin loads before FMA block
#pragma unroll 2
        for (int k = 0; k < 16; ++k) {            // k ascending: exact dot chain
            const float* xr = xB + (kc * 16 + k) * 68 + 8 * tr7 + 4 * (tr7 >> 2);
            float4 xa = *(const float4*)(xr);
            float4 xb = *(const float4*)(xr + 4);
            const float* er = eW + k * 160 + 20 * tcw;
            float4 e0 = *(const float4*)(er);
            float4 e1 = *(const float4*)(er + 4);
            float4 e2 = *(const float4*)(er + 8);
            float4 e3 = *(const float4*)(er + 12);
            FMA16(0, xa.x) FMA16(1, xa.y) FMA16(2, xa.z) FMA16(3, xa.w)
            FMA16(4, xb.x) FMA16(5, xb.y) FMA16(6, xb.z) FMA16(7, xb.w)
        }
    }
#undef FMA16
#undef LOADE
#undef WRITEE

    // per-thread argmin over its 16 codes (ci ascending, strict <)
    const int cb0 = wcode + tcw * 16;
    float best[8];
    int bi[8];
#pragma unroll
    for (int ri = 0; ri < 8; ++ri) { best[ri] = FLT_MAX; bi[ri] = 0; }
#pragma unroll
    for (int ci = 0; ci < 16; ++ci) {
        float ec = eeL[cb0 + ci];
#pragma unroll
        for (int ri = 0; ri < 8; ++ri) {
            float dd = (VV8(ri) - 2.f * acc[ri][ci]) + ec;
            if (dd < best[ri]) { best[ri] = dd; bi[ri] = cb0 + ci; }
        }
    }

    __syncthreads();                              // all compute done; reuse xB
    float* redB = smem;                           // [32][65]
    int*   redI = (int*)(smem + 2080);            // [32][65]
    const int cand = wv * 8 + tcw;                // code-ascending candidate id
#pragma unroll
    for (int ri = 0; ri < 8; ++ri) {
        redB[cand * 65 + 8 * tr7 + ri] = best[ri];
        redI[cand * 65 + 8 * tr7 + ri] = bi[ri];
    }
    __syncthreads();

    if (tid < 64) {
        float bb = redB[tid];
        int bix = redI[tid];
#pragma unroll
        for (int c = 1; c < 32; ++c) {
            float b = redB[c * 65 + tid];
            int i = redI[c * 65 + tid];
            if (b < bb || (b == bb && i < bix)) { bb = b; bix = i; }
        }

        const int row = brow + tid;
        float lg[ADIM];
#pragma unroll
        for (int a = 0; a < ADIM; ++a) lg[a] = ba[a];
        float val = bv[0];

        const float4* q4 = (const float4*)(emb + (size_t)bix * HDIM);
#pragma unroll
        for (int j4 = 0; j4 < HDIM / 4; ++j4) {
            float4 q = q4[j4];
            const int j = 4 * j4;
#pragma unroll
            for (int a = 0; a < ADIM; ++a) {
                float t = lg[a];
                t = fmaf(q.x, Wa[(j + 0) * ADIM + a], t);
                t = fmaf(q.y, Wa[(j + 1) * ADIM + a], t);
                t = fmaf(q.z, Wa[(j + 2) * ADIM + a], t);
                t = fmaf(q.w, Wa[(j + 3) * ADIM + a], t);
                lg[a] = t;
            }
            val = fmaf(q.x, Wv[j + 0], val);
            val = fmaf(q.y, Wv[j + 1], val);
            val = fmaf(q.z, Wv[j + 2], val);
            val = fmaf(q.w, Wv[j + 3], val);
        }

        float m = lg[0];
#pragma unroll
        for (int a = 1; a < ADIM; ++a) m = fmaxf(m, lg[a]);
        float p[ADIM];
        float s = 0.f;
#pragma unroll
        for (int a = 0; a < ADIM; ++a) { p[a] = __expf(lg[a] - m); s += p[a]; }
        const float inv = 1.f / s;

        float4* outp = (float4*)(out + (size_t)row * ADIM);
        outp[0] = make_float4(p[0] * inv, p[1] * inv, p[2] * inv, p[3] * inv);
        outp[1] = make_float4(p[4] * inv, p[5] * inv, p[6] * inv, p[7] * inv);
        out[(size_t)NROWS * ADIM + row] = val;
    }
}

// ===========================================================================
// Fallback (ws too small; never expected): round-4 global-feed path.
// ===========================================================================
#define R16(M) M(0) M(1) M(2) M(3) M(4) M(5) M(6) M(7) \
               M(8) M(9) M(10) M(11) M(12) M(13) M(14) M(15)
#define R32(M) R16(M) M(16) M(17) M(18) M(19) M(20) M(21) M(22) M(23) \
               M(24) M(25) M(26) M(27) M(28) M(29) M(30) M(31)
#define PIN4(v) asm volatile("" : "+v"(v.x), "+v"(v.y), "+v"(v.z), "+v"(v.w));

__global__ __launch_bounds__(256, 2) void fused_global_kernel(
    const float* __restrict__ in,
    const float* __restrict__ W1, const float* __restrict__ b1,
    const float* __restrict__ Wh, const float* __restrict__ bh,
    const float* __restrict__ emb,
    const float* __restrict__ Wa, const float* __restrict__ ba,
    const float* __restrict__ Wv, const float* __restrict__ bv,
    float* __restrict__ out)
{
    __shared__ float ee_s[KCODES];
    const int tid = threadIdx.x;
    const int row = blockIdx.x * 256 + tid;

#pragma unroll
    for (int kk = 0; kk < 2; ++kk) {
        int k = tid + 256 * kk;
        const float* e = emb + k * HDIM;
        float a0 = 0.f, a1 = 0.f, a2 = 0.f, a3 = 0.f;
#pragma unroll
        for (int j = 0; j < HDIM; j += 4) {
            a0 = fmaf(e[j + 0], e[j + 0], a0);
            a1 = fmaf(e[j + 1], e[j + 1], a1);
            a2 = fmaf(e[j + 2], e[j + 2], a2);
            a3 = fmaf(e[j + 3], e[j + 3], a3);
        }
        ee_s[k] = (a0 + a1) + (a2 + a3);
    }
    __syncthreads();

    const float4* inr4 = (const float4*)(in + (size_t)row * SDIM);
#define DECLI(n) float4 i##n = inr4[n]; PIN4(i##n)
    R16(DECLI)
#define DECLX(m) float4 x##m = make_float4(bh[4*(m)+0], bh[4*(m)+1], bh[4*(m)+2], bh[4*(m)+3]);
    R32(DECLX)

#define L1N(n) xt = fmaf(i##n.x, wc[(4*(n)+0)*HDIM], xt); xt = fmaf(i##n.y, wc[(4*(n)+1)*HDIM], xt); \
               xt = fmaf(i##n.z, wc[(4*(n)+2)*HDIM], xt); xt = fmaf(i##n.w, wc[(4*(n)+3)*HDIM], xt);
#define L2(m)  x##m.x = fmaf(xt, whr[4*(m)+0], x##m.x); x##m.y = fmaf(xt, whr[4*(m)+1], x##m.y); \
               x##m.z = fmaf(xt, whr[4*(m)+2], x##m.z); x##m.w = fmaf(xt, whr[4*(m)+3], x##m.w);
    for (int t = 0; t < HDIM; ++t) {
        float xt = b1[t];
        const float* wc = W1 + t;
        R16(L1N)
        xt = fmaxf(xt, 0.f);
        const float* whr = Wh + t * HDIM;
        R32(L2)
    }
#define RELUX(m) x##m.x = fmaxf(x##m.x, 0.f); x##m.y = fmaxf(x##m.y, 0.f); \
                 x##m.z = fmaxf(x##m.z, 0.f); x##m.w = fmaxf(x##m.w, 0.f); PIN4(x##m)
    R32(RELUX)

    float v0 = 0.f, v1 = 0.f, v2 = 0.f, v3 = 0.f;
#define VV(m) v0 = fmaf(x##m.x, x##m.x, v0); v1 = fmaf(x##m.y, x##m.y, v1); \
              v2 = fmaf(x##m.z, x##m.z, v2); v3 = fmaf(x##m.w, x##m.w, v3);
    R32(VV)
    const float vv = (v0 + v1) + (v2 + v3);

    float best = FLT_MAX;
    int bi = 0;
#define SC(m) \
    d0 = fmaf(x##m.x, eb[0*HDIM+4*(m)+0], d0); d0 = fmaf(x##m.y, eb[0*HDIM+4*(m)+1], d0); \
    d0 = fmaf(x##m.z, eb[0*HDIM+4*(m)+2], d0); d0 = fmaf(x##m.w, eb[0*HDIM+4*(m)+3], d0); \
    d1 = fmaf(x##m.x, eb[1*HDIM+4*(m)+0], d1); d1 = fmaf(x##m.y, eb[1*HDIM+4*(m)+1], d1); \
    d1 = fmaf(x##m.z, eb[1*HDIM+4*(m)+2], d1); d1 = fmaf(x##m.w, eb[1*HDIM+4*(m)+3], d1); \
    d2 = fmaf(x##m.x, eb[2*HDIM+4*(m)+0], d2); d2 = fmaf(x##m.y, eb[2*HDIM+4*(m)+1], d2); \
    d2 = fmaf(x##m.z, eb[2*HDIM+4*(m)+2], d2); d2 = fmaf(x##m.w, eb[2*HDIM+4*(m)+3], d2); \
    d3 = fmaf(x##m.x, eb[3*HDIM+4*(m)+0], d3); d3 = fmaf(x##m.y, eb[3*HDIM+4*(m)+1], d3); \
    d3 = fmaf(x##m.z, eb[3*HDIM+4*(m)+2], d3); d3 = fmaf(x##m.w, eb[3*HDIM+4*(m)+3], d3); \
    d4 = fmaf(x##m.x, eb[4*HDIM+4*(m)+0], d4); d4 = fmaf(x##m.y, eb[4*HDIM+4*(m)+1], d4); \
    d4 = fmaf(x##m.z, eb[4*HDIM+4*(m)+2], d4); d4 = fmaf(x##m.w, eb[4*HDIM+4*(m)+3], d4); \
    d5 = fmaf(x##m.x, eb[5*HDIM+4*(m)+0], d5); d5 = fmaf(x##m.y, eb[5*HDIM+4*(m)+1], d5); \
    d5 = fmaf(x##m.z, eb[5*HDIM+4*(m)+2], d5); d5 = fmaf(x##m.w, eb[5*HDIM+4*(m)+3], d5); \
    d6 = fmaf(x##m.x, eb[6*HDIM+4*(m)+0], d6); d6 = fmaf(x##m.y, eb[6*HDIM+4*(m)+1], d6); \
    d6 = fmaf(x##m.z, eb[6*HDIM+4*(m)+2], d6); d6 = fmaf(x##m.w, eb[6*HDIM+4*(m)+3], d6); \
    d7 = fmaf(x##m.x, eb[7*HDIM+4*(m)+0], d7); d7 = fmaf(x##m.y, eb[7*HDIM+4*(m)+1], d7); \
    d7 = fmaf(x##m.z, eb[7*HDIM+4*(m)+2], d7); d7 = fmaf(x##m.w, eb[7*HDIM+4*(m)+3], d7);
    for (int k0 = 0; k0 < KCODES; k0 += 8) {
        const float* eb = emb + (size_t)k0 * HDIM;
        float d0 = 0.f, d1 = 0.f, d2 = 0.f, d3 = 0.f;
        float d4 = 0.f, d5 = 0.f, d6 = 0.f, d7 = 0.f;
        R32(SC)
        float dd;
        dd = (vv - 2.f * d0) + ee_s[k0 + 0]; if (dd < best) { best = dd; bi = k0 + 0; }
        dd = (vv - 2.f * d1) + ee_s[k0 + 1]; if (dd < best) { best = dd; bi = k0 + 1; }
        dd = (vv - 2.f * d2) + ee_s[k0 + 2]; if (dd < best) { best = dd; bi = k0 + 2; }
        dd = (vv - 2.f * d3) + ee_s[k0 + 3]; if (dd < best) { best = dd; bi = k0 + 3; }
        dd = (vv - 2.f * d4) + ee_s[k0 + 4]; if (dd < best) { best = dd; bi = k0 + 4; }
        dd = (vv - 2.f * d5) + ee_s[k0 + 5]; if (dd < best) { best = dd; bi = k0 + 5; }
        dd = (vv - 2.f * d6) + ee_s[k0 + 6]; if (dd < best) { best = dd; bi = k0 + 6; }
        dd = (vv - 2.f * d7) + ee_s[k0 + 7]; if (dd < best) { best = dd; bi = k0 + 7; }
    }

    float lg[ADIM];
#pragma unroll
    for (int a = 0; a < ADIM; ++a) lg[a] = ba[a];
    float val = bv[0];
    const float4* q4 = (const float4*)(emb + (size_t)bi * HDIM);
#pragma unroll
    for (int j4 = 0; j4 < HDIM / 4; ++j4) {
        float4 q = q4[j4];
        const int j = 4 * j4;
#pragma unroll
        for (int a = 0; a < ADIM; ++a) {
            float t = lg[a];
            t = fmaf(q.x, Wa[(j + 0) * ADIM + a], t);
            t = fmaf(q.y, Wa[(j + 1) * ADIM + a], t);
            t = fmaf(q.z, Wa[(j + 2) * ADIM + a], t);
            t = fmaf(q.w, Wa[(j + 3) * ADIM + a], t);
            lg[a] = t;
        }
        val = fmaf(q.x, Wv[j + 0], val);
        val = fmaf(q.y, Wv[j + 1], val);
        val = fmaf(q.z, Wv[j + 2], val);
        val = fmaf(q.w, Wv[j + 3], val);
    }
    float m = lg[0];
#pragma unroll
    for (int a = 1; a < ADIM; ++a) m = fmaxf(m, lg[a]);
    float p[ADIM];
    float s = 0.f;
#pragma unroll
    for (int a = 0; a < ADIM; ++a) { p[a] = __expf(lg[a] - m); s += p[a]; }
    const float inv = 1.f / s;
    float4* outp = (float4*)(out + (size_t)row * ADIM);
    outp[0] = make_float4(p[0] * inv, p[1] * inv, p[2] * inv, p[3] * inv);
    outp[1] = make_float4(p[4] * inv, p[5] * inv, p[6] * inv, p[7] * inv);
    out[(size_t)NROWS * ADIM + row] = val;
}

// ===========================================================================
extern "C" void kernel_launch(void* const* d_in, const int* in_sizes, int n_in,
                              void* d_out, int out_size, void* d_ws, size_t ws_size,
                              hipStream_t stream) {
    const float* in  = (const float*)d_in[0];
    const float* W1  = (const float*)d_in[1];
    const float* b1  = (const float*)d_in[2];
    const float* Wh  = (const float*)d_in[3];
    const float* bh  = (const float*)d_in[4];
    const float* emb = (const float*)d_in[5];
    const float* Wa  = (const float*)d_in[6];
    const float* ba  = (const float*)d_in[7];
    const float* Wv  = (const float*)d_in[8];
    const float* bv  = (const float*)d_in[9];
    float* out = (float*)d_out;

    const size_t x2_f = (size_t)NROWS * HDIM;             // 64 MB
    const size_t eT_f = (size_t)KCODES * HDIM;            // 256 KB
    const size_t ee_f = KCODES;                           // 2 KB
    const size_t vv_f = NROWS;                            // 512 KB
    const size_t need = (x2_f + eT_f + ee_f + vv_f) * sizeof(float);

    if (ws_size >= need) {
        float* x2t = (float*)d_ws;
        float* eTp = x2t + x2_f;
        float* eew = eTp + eT_f;
        float* vvs = eew + ee_f;
        prep_e_kernel<<<64, 256, 0, stream>>>(emb, eTp);
        ee_kernel<<<2, 256, 0, stream>>>(emb, eew);
        mlp_kernel<<<NROWS / 64, 256, 0, stream>>>(in, W1, b1, Wh, bh, x2t, vvs, NROWS);
        vq_kernel<<<NROWS / 64, 256, 0, stream>>>(x2t, eTp, eew, vvs, emb,
                                                  Wa, ba, Wv, bv, out, NROWS);
    } else {
        fused_global_kernel<<<NROWS / 256, 256, 0, stream>>>(in, W1, b1, Wh, bh, emb,
                                                             Wa, ba, Wv, bv, out);
    }
}

// Round 9
// 345.496 us; speedup vs baseline: 1.0360x; 1.0360x over previous
//
#include <hip/hip_runtime.h>
#include <math.h>
#include <float.h>

#define NROWS 131072
#define SDIM 64
#define HDIM 128
#define KCODES 512
#define ADIM 8

// ===========================================================================
// MLP (round-5 structure) + folded prep work (round 9):
//  - blocks 0..63  additionally produce eT[j][c] = emb[c][j] (prep_e fold)
//  - blocks 64..65 additionally produce ee[k] = sum_j emb[k][j]^2 (ee fold)
// Both use the exact same code/chains as the former standalone kernels —
// bit-exact; visibility to vq_kernel is guaranteed by stream ordering
// (same as the former separate launches). Saves 2 launches.
// MLP proper: 64-row blocks, shared [128][65] region, launch_bounds(256,3).
// Lane l owns row l; wave wu owns cols [wu*32,+32). Chains exact (s-asc,
// t-asc); vv grouping ((p0+p1)+p2)+p3 — bit-exact.
// ===========================================================================
__global__ __launch_bounds__(256, 3) void mlp_kernel(
    const float* __restrict__ in,
    const float* __restrict__ W1, const float* __restrict__ b1,
    const float* __restrict__ Wh, const float* __restrict__ bh,
    float* __restrict__ x2t, float* __restrict__ vvs, int rstride,
    const float* __restrict__ emb, float* __restrict__ eT,
    float* __restrict__ ee)
{
    __shared__ float buf[8320];                   // [128][65] = 33.3 KB
    const int tid = threadIdx.x;
    const int wu = __builtin_amdgcn_readfirstlane(tid >> 6);
    const int l = tid & 63;
    const int brow = blockIdx.x * 64;
    const int c0 = wu * 32;

    {   // stage in^T: buf[s][r] = in[brow+r][s], [64][65]
        const float4* src = (const float4*)(in + (size_t)brow * SDIM);
#pragma unroll
        for (int u = 0; u < 4; ++u) {
            int idx = tid + 256 * u;              // 0..1023
            int r = idx >> 4, s4 = idx & 15;
            float4 v = src[idx];
            buf[(4 * s4 + 0) * 65 + r] = v.x;
            buf[(4 * s4 + 1) * 65 + r] = v.y;
            buf[(4 * s4 + 2) * 65 + r] = v.z;
            buf[(4 * s4 + 3) * 65 + r] = v.w;
        }
    }
    __syncthreads();

    float acc[32];
#pragma unroll
    for (int cc = 0; cc < 32; ++cc) acc[cc] = b1[c0 + cc];
#pragma unroll 4
    for (int s = 0; s < SDIM; ++s) {              // s ascending: exact chain
        float xa = buf[s * 65 + l];
        const float* wr = W1 + s * HDIM + c0;     // uniform -> s_load
#pragma unroll
        for (int cc = 0; cc < 32; ++cc) acc[cc] = fmaf(xa, wr[cc], acc[cc]);
    }
    __syncthreads();                              // in-buf reads done; reuse
#pragma unroll
    for (int cc = 0; cc < 32; ++cc)
        buf[(c0 + cc) * 65 + l] = fmaxf(acc[cc], 0.f);
    __syncthreads();

#pragma unroll
    for (int cc = 0; cc < 32; ++cc) acc[cc] = bh[c0 + cc];
#pragma unroll 4
    for (int t = 0; t < HDIM; ++t) {              // t ascending: exact chain
        float xa = buf[t * 65 + l];
        const float* wr = Wh + t * HDIM + c0;     // uniform -> s_load
#pragma unroll
        for (int cc = 0; cc < 32; ++cc) acc[cc] = fmaf(xa, wr[cc], acc[cc]);
    }
    float pa = 0.f;
#pragma unroll
    for (int cc = 0; cc < 32; ++cc) {
        float a = fmaxf(acc[cc], 0.f);
        x2t[(size_t)(c0 + cc) * rstride + brow + l] = a;
        pa = fmaf(a, a, pa);
    }
    __syncthreads();                              // x1 reads done; reuse buf
    buf[wu * 64 + l] = pa;
    __syncthreads();
    if (tid < 64) {
        float vv = ((buf[tid] + buf[64 + tid]) + buf[128 + tid]) + buf[192 + tid];
        vvs[brow + tid] = vv;
    }

    // ---- folded prep_e (blocks 0..63): eT[j][c] = emb[c][j] ----
    if (blockIdx.x < 64) {
        int g = blockIdx.x * 256 + tid;           // 0..16383
        int c = g >> 5, j4 = g & 31;
        float4 v = ((const float4*)emb)[(size_t)c * 32 + j4];
        eT[(size_t)(4 * j4 + 0) * KCODES + c] = v.x;
        eT[(size_t)(4 * j4 + 1) * KCODES + c] = v.y;
        eT[(size_t)(4 * j4 + 2) * KCODES + c] = v.z;
        eT[(size_t)(4 * j4 + 3) * KCODES + c] = v.w;
    } else if (blockIdx.x < 66) {
        // ---- folded ee (blocks 64..65): ee[k] = sum_j emb[k][j]^2 ----
        int k = (blockIdx.x - 64) * 256 + tid;    // 0..511
        const float* e = emb + k * HDIM;
        float a0 = 0.f, a1 = 0.f, a2 = 0.f, a3 = 0.f;
#pragma unroll
        for (int j = 0; j < HDIM; j += 4) {
            a0 = fmaf(e[j + 0], e[j + 0], a0);
            a1 = fmaf(e[j + 1], e[j + 1], a1);
            a2 = fmaf(e[j + 2], e[j + 2], a2);
            a3 = fmaf(e[j + 3], e[j + 3], a3);
        }
        ee[k] = (a0 + a1) + (a2 + a3);
    }
}

// ===========================================================================
// VQ — Round 9: exact round-7 best-measured variant (215.3 us). R8's two
// edits (x-slot swizzle, T14 reg-prefetch + sched_barrier) REVERTED: the
// 4.46M conflict counter is only ~0.85% of runtime (wrongly chased), and
// the pinned prefetch defeated the compiler's schedule (-10%, VALUBusy
// 71->63). Structure:
//  - block = 64 rows x 512 codes; wave w owns codes [w*128,+128) (private).
//  - x staged ONCE for full K ([128][68]) behind the only barrier.
//  - per chunk: stage private [16][160] e-slice (col swizzle c+4*(c>>4) ->
//    reads hit all 32 banks once), then 16 k-steps x 128 FMA; NO cross-wave
//    barriers; intra-wave LDS in-order + compiler lgkmcnt.
//  - final barrier -> cross-wave argmin (strict <, index tie-break).
// LDS 77,824 B -> 2 blocks/CU. Dot chain k 0..127 ascending, single acc per
// (row,code) — bit-exact. Heads inline (exact chain).
// ===========================================================================
#define VV8(ri) ((ri)==0?vv0.x:(ri)==1?vv0.y:(ri)==2?vv0.z:(ri)==3?vv0.w: \
                 (ri)==4?vv1.x:(ri)==5?vv1.y:(ri)==6?vv1.z:vv1.w)

__global__ __launch_bounds__(256, 1) void vq_kernel(
    const float* __restrict__ x2t, const float* __restrict__ eT,
    const float* __restrict__ eew, const float* __restrict__ vvs,
    const float* __restrict__ emb,
    const float* __restrict__ Wa, const float* __restrict__ ba,
    const float* __restrict__ Wv, const float* __restrict__ bv,
    float* __restrict__ out, int rstride)
{
    __shared__ float smem[19456];                 // 77824 B
    float* xB  = smem;                            // [128][68] = 8704
    float* eB  = smem + 8704;                     // 4 x wave-private [16][160]
    float* eeL = smem + 18944;                    // [512]
    const int tid  = threadIdx.x;
    const int lane = tid & 63;
    const int wv   = __builtin_amdgcn_readfirstlane(tid >> 6);
    const int tr7  = lane & 7;                    // rows 8*tr7 .. +7
    const int tcw  = lane >> 3;                   // 0..7: 16-code group
    const int brow = blockIdx.x * 64;
    const int wcode = wv * 128;

    eeL[tid]       = eew[tid];
    eeL[tid + 256] = eew[tid + 256];

    {   // stage x for FULL K (once; cb-independent)
#pragma unroll
        for (int u = 0; u < 8; ++u) {
            int idx = tid + 256 * u;              // 0..2047
            int kk = idx >> 4, rq = idx & 15;
            float4 xv = *(const float4*)(x2t + (size_t)kk * rstride + brow + 4 * rq);
            *(float4*)(xB + kk * 68 + 4 * rq) = xv;
        }
    }
    __syncthreads();                              // the ONLY pre-reduction barrier

    float4 vv0 = *(const float4*)(vvs + brow + 8 * tr7);
    float4 vv1 = *(const float4*)(vvs + brow + 8 * tr7 + 4);

    float acc[8][16];
#pragma unroll
    for (int ri = 0; ri < 8; ++ri)
#pragma unroll
        for (int ci = 0; ci < 16; ++ci) acc[ri][ci] = 0.f;

    float* eW = eB + wv * 2560;                   // this wave's [16][160]

#define FMA16(ri, xv) \
    acc[ri][0]  = fmaf(xv, e0.x, acc[ri][0]);  acc[ri][1]  = fmaf(xv, e0.y, acc[ri][1]);  \
    acc[ri][2]  = fmaf(xv, e0.z, acc[ri][2]);  acc[ri][3]  = fmaf(xv, e0.w, acc[ri][3]);  \
    acc[ri][4]  = fmaf(xv, e1.x, acc[ri][4]);  acc[ri][5]  = fmaf(xv, e1.y, acc[ri][5]);  \
    acc[ri][6]  = fmaf(xv, e1.z, acc[ri][6]);  acc[ri][7]  = fmaf(xv, e1.w, acc[ri][7]);  \
    acc[ri][8]  = fmaf(xv, e2.x, acc[ri][8]);  acc[ri][9]  = fmaf(xv, e2.y, acc[ri][9]);  \
    acc[ri][10] = fmaf(xv, e2.z, acc[ri][10]); acc[ri][11] = fmaf(xv, e2.w, acc[ri][11]); \
    acc[ri][12] = fmaf(xv, e3.x, acc[ri][12]); acc[ri][13] = fmaf(xv, e3.y, acc[ri][13]); \
    acc[ri][14] = fmaf(xv, e3.z, acc[ri][14]); acc[ri][15] = fmaf(xv, e3.w, acc[ri][15]);

    for (int kc = 0; kc < 8; ++kc) {              // 8 chunks x 16 k; NO barriers
        // wave-private e staging, swizzled: col c -> slot c + 4*(c>>4)
        // (slots 20*t mod 32 all distinct -> reads hit all 32 banks once).
#pragma unroll
        for (int u = 0; u < 8; ++u) {
            int idx = lane + 64 * u;              // 0..511
            int kk = idx >> 5, rq = idx & 31;     // kk 0..15, c = 4*rq
            float4 ev = *(const float4*)(eT + (size_t)(kc * 16 + kk) * KCODES + wcode + 4 * rq);
            *(float4*)(eW + kk * 160 + 4 * rq + 4 * (rq >> 2)) = ev;
        }
#pragma unroll 2
        for (int k = 0; k < 16; ++k) {            // k ascending: exact dot chain
            const float* xr = xB + (kc * 16 + k) * 68 + 8 * tr7;
            float4 xa = *(const float4*)(xr);
            float4 xb = *(const float4*)(xr + 4);
            const float* er = eW + k * 160 + 20 * tcw;
            float4 e0 = *(const float4*)(er);
            float4 e1 = *(const float4*)(er + 4);
            float4 e2 = *(const float4*)(er + 8);
            float4 e3 = *(const float4*)(er + 12);
            FMA16(0, xa.x) FMA16(1, xa.y) FMA16(2, xa.z) FMA16(3, xa.w)
            FMA16(4, xb.x) FMA16(5, xb.y) FMA16(6, xb.z) FMA16(7, xb.w)
        }
    }
#undef FMA16

    // per-thread argmin over its 16 codes (ci ascending, strict <)
    const int cb0 = wcode + tcw * 16;
    float best[8];
    int bi[8];
#pragma unroll
    for (int ri = 0; ri < 8; ++ri) { best[ri] = FLT_MAX; bi[ri] = 0; }
#pragma unroll
    for (int ci = 0; ci < 16; ++ci) {
        float ec = eeL[cb0 + ci];
#pragma unroll
        for (int ri = 0; ri < 8; ++ri) {
            float dd = (VV8(ri) - 2.f * acc[ri][ci]) + ec;
            if (dd < best[ri]) { best[ri] = dd; bi[ri] = cb0 + ci; }
        }
    }

    __syncthreads();                              // all compute done; reuse xB
    float* redB = smem;                           // [32][65]
    int*   redI = (int*)(smem + 2080);            // [32][65]
    const int cand = wv * 8 + tcw;                // code-ascending candidate id
#pragma unroll
    for (int ri = 0; ri < 8; ++ri) {
        redB[cand * 65 + 8 * tr7 + ri] = best[ri];
        redI[cand * 65 + 8 * tr7 + ri] = bi[ri];
    }
    __syncthreads();

    if (tid < 64) {
        float bb = redB[tid];
        int bix = redI[tid];
#pragma unroll
        for (int c = 1; c < 32; ++c) {
            float b = redB[c * 65 + tid];
            int i = redI[c * 65 + tid];
            if (b < bb || (b == bb && i < bix)) { bb = b; bix = i; }
        }

        const int row = brow + tid;
        float lg[ADIM];
#pragma unroll
        for (int a = 0; a < ADIM; ++a) lg[a] = ba[a];
        float val = bv[0];

        const float4* q4 = (const float4*)(emb + (size_t)bix * HDIM);
#pragma unroll
        for (int j4 = 0; j4 < HDIM / 4; ++j4) {
            float4 q = q4[j4];
            const int j = 4 * j4;
#pragma unroll
            for (int a = 0; a < ADIM; ++a) {
                float t = lg[a];
                t = fmaf(q.x, Wa[(j + 0) * ADIM + a], t);
                t = fmaf(q.y, Wa[(j + 1) * ADIM + a], t);
                t = fmaf(q.z, Wa[(j + 2) * ADIM + a], t);
                t = fmaf(q.w, Wa[(j + 3) * ADIM + a], t);
                lg[a] = t;
            }
            val = fmaf(q.x, Wv[j + 0], val);
            val = fmaf(q.y, Wv[j + 1], val);
            val = fmaf(q.z, Wv[j + 2], val);
            val = fmaf(q.w, Wv[j + 3], val);
        }

        float m = lg[0];
#pragma unroll
        for (int a = 1; a < ADIM; ++a) m = fmaxf(m, lg[a]);
        float p[ADIM];
        float s = 0.f;
#pragma unroll
        for (int a = 0; a < ADIM; ++a) { p[a] = __expf(lg[a] - m); s += p[a]; }
        const float inv = 1.f / s;

        float4* outp = (float4*)(out + (size_t)row * ADIM);
        outp[0] = make_float4(p[0] * inv, p[1] * inv, p[2] * inv, p[3] * inv);
        outp[1] = make_float4(p[4] * inv, p[5] * inv, p[6] * inv, p[7] * inv);
        out[(size_t)NROWS * ADIM + row] = val;
    }
}

// ===========================================================================
// Fallback (ws too small; never expected): round-4 global-feed path.
// ===========================================================================
#define R16(M) M(0) M(1) M(2) M(3) M(4) M(5) M(6) M(7) \
               M(8) M(9) M(10) M(11) M(12) M(13) M(14) M(15)
#define R32(M) R16(M) M(16) M(17) M(18) M(19) M(20) M(21) M(22) M(23) \
               M(24) M(25) M(26) M(27) M(28) M(29) M(30) M(31)
#define PIN4(v) asm volatile("" : "+v"(v.x), "+v"(v.y), "+v"(v.z), "+v"(v.w));

__global__ __launch_bounds__(256, 2) void fused_global_kernel(
    const float* __restrict__ in,
    const float* __restrict__ W1, const float* __restrict__ b1,
    const float* __restrict__ Wh, const float* __restrict__ bh,
    const float* __restrict__ emb,
    const float* __restrict__ Wa, const float* __restrict__ ba,
    const float* __restrict__ Wv, const float* __restrict__ bv,
    float* __restrict__ out)
{
    __shared__ float ee_s[KCODES];
    const int tid = threadIdx.x;
    const int row = blockIdx.x * 256 + tid;

#pragma unroll
    for (int kk = 0; kk < 2; ++kk) {
        int k = tid + 256 * kk;
        const float* e = emb + k * HDIM;
        float a0 = 0.f, a1 = 0.f, a2 = 0.f, a3 = 0.f;
#pragma unroll
        for (int j = 0; j < HDIM; j += 4) {
            a0 = fmaf(e[j + 0], e[j + 0], a0);
            a1 = fmaf(e[j + 1], e[j + 1], a1);
            a2 = fmaf(e[j + 2], e[j + 2], a2);
            a3 = fmaf(e[j + 3], e[j + 3], a3);
        }
        ee_s[k] = (a0 + a1) + (a2 + a3);
    }
    __syncthreads();

    const float4* inr4 = (const float4*)(in + (size_t)row * SDIM);
#define DECLI(n) float4 i##n = inr4[n]; PIN4(i##n)
    R16(DECLI)
#define DECLX(m) float4 x##m = make_float4(bh[4*(m)+0], bh[4*(m)+1], bh[4*(m)+2], bh[4*(m)+3]);
    R32(DECLX)

#define L1N(n) xt = fmaf(i##n.x, wc[(4*(n)+0)*HDIM], xt); xt = fmaf(i##n.y, wc[(4*(n)+1)*HDIM], xt); \
               xt = fmaf(i##n.z, wc[(4*(n)+2)*HDIM], xt); xt = fmaf(i##n.w, wc[(4*(n)+3)*HDIM], xt);
#define L2(m)  x##m.x = fmaf(xt, whr[4*(m)+0], x##m.x); x##m.y = fmaf(xt, whr[4*(m)+1], x##m.y); \
               x##m.z = fmaf(xt, whr[4*(m)+2], x##m.z); x##m.w = fmaf(xt, whr[4*(m)+3], x##m.w);
    for (int t = 0; t < HDIM; ++t) {
        float xt = b1[t];
        const float* wc = W1 + t;
        R16(L1N)
        xt = fmaxf(xt, 0.f);
        const float* whr = Wh + t * HDIM;
        R32(L2)
    }
#define RELUX(m) x##m.x = fmaxf(x##m.x, 0.f); x##m.y = fmaxf(x##m.y, 0.f); \
                 x##m.z = fmaxf(x##m.z, 0.f); x##m.w = fmaxf(x##m.w, 0.f); PIN4(x##m)
    R32(RELUX)

    float v0 = 0.f, v1 = 0.f, v2 = 0.f, v3 = 0.f;
#define VV(m) v0 = fmaf(x##m.x, x##m.x, v0); v1 = fmaf(x##m.y, x##m.y, v1); \
              v2 = fmaf(x##m.z, x##m.z, v2); v3 = fmaf(x##m.w, x##m.w, v3);
    R32(VV)
    const float vv = (v0 + v1) + (v2 + v3);

    float best = FLT_MAX;
    int bi = 0;
#define SC(m) \
    d0 = fmaf(x##m.x, eb[0*HDIM+4*(m)+0], d0); d0 = fmaf(x##m.y, eb[0*HDIM+4*(m)+1], d0); \
    d0 = fmaf(x##m.z, eb[0*HDIM+4*(m)+2], d0); d0 = fmaf(x##m.w, eb[0*HDIM+4*(m)+3], d0); \
    d1 = fmaf(x##m.x, eb[1*HDIM+4*(m)+0], d1); d1 = fmaf(x##m.y, eb[1*HDIM+4*(m)+1], d1); \
    d1 = fmaf(x##m.z, eb[1*HDIM+4*(m)+2], d1); d1 = fmaf(x##m.w, eb[1*HDIM+4*(m)+3], d1); \
    d2 = fmaf(x##m.x, eb[2*HDIM+4*(m)+0], d2); d2 = fmaf(x##m.y, eb[2*HDIM+4*(m)+1], d2); \
    d2 = fmaf(x##m.z, eb[2*HDIM+4*(m)+2], d2); d2 = fmaf(x##m.w, eb[2*HDIM+4*(m)+3], d2); \
    d3 = fmaf(x##m.x, eb[3*HDIM+4*(m)+0], d3); d3 = fmaf(x##m.y, eb[3*HDIM+4*(m)+1], d3); \
    d3 = fmaf(x##m.z, eb[3*HDIM+4*(m)+2], d3); d3 = fmaf(x##m.w, eb[3*HDIM+4*(m)+3], d3); \
    d4 = fmaf(x##m.x, eb[4*HDIM+4*(m)+0], d4); d4 = fmaf(x##m.y, eb[4*HDIM+4*(m)+1], d4); \
    d4 = fmaf(x##m.z, eb[4*HDIM+4*(m)+2], d4); d4 = fmaf(x##m.w, eb[4*HDIM+4*(m)+3], d4); \
    d5 = fmaf(x##m.x, eb[5*HDIM+4*(m)+0], d5); d5 = fmaf(x##m.y, eb[5*HDIM+4*(m)+1], d5); \
    d5 = fmaf(x##m.z, eb[5*HDIM+4*(m)+2], d5); d5 = fmaf(x##m.w, eb[5*HDIM+4*(m)+3], d5); \
    d6 = fmaf(x##m.x, eb[6*HDIM+4*(m)+0], d6); d6 = fmaf(x##m.y, eb[6*HDIM+4*(m)+1], d6); \
    d6 = fmaf(x##m.z, eb[6*HDIM+4*(m)+2], d6); d6 = fmaf(x##m.w, eb[6*HDIM+4*(m)+3], d6); \
    d7 = fmaf(x##m.x, eb[7*HDIM+4*(m)+0], d7); d7 = fmaf(x##m.y, eb[7*HDIM+4*(m)+1], d7); \
    d7 = fmaf(x##m.z, eb[7*HDIM+4*(m)+2], d7); d7 = fmaf(x##m.w, eb[7*HDIM+4*(m)+3], d7);
    for (int k0 = 0; k0 < KCODES; k0 += 8) {
        const float* eb = emb + (size_t)k0 * HDIM;
        float d0 = 0.f, d1 = 0.f, d2 = 0.f, d3 = 0.f;
        float d4 = 0.f, d5 = 0.f, d6 = 0.f, d7 = 0.f;
        R32(SC)
        float dd;
        dd = (vv - 2.f * d0) + ee_s[k0 + 0]; if (dd < best) { best = dd; bi = k0 + 0; }
        dd = (vv - 2.f * d1) + ee_s[k0 + 1]; if (dd < best) { best = dd; bi = k0 + 1; }
        dd = (vv - 2.f * d2) + ee_s[k0 + 2]; if (dd < best) { best = dd; bi = k0 + 2; }
        dd = (vv - 2.f * d3) + ee_s[k0 + 3]; if (dd < best) { best = dd; bi = k0 + 3; }
        dd = (vv - 2.f * d4) + ee_s[k0 + 4]; if (dd < best) { best = dd; bi = k0 + 4; }
        dd = (vv - 2.f * d5) + ee_s[k0 + 5]; if (dd < best) { best = dd; bi = k0 + 5; }
        dd = (vv - 2.f * d6) + ee_s[k0 + 6]; if (dd < best) { best = dd; bi = k0 + 6; }
        dd = (vv - 2.f * d7) + ee_s[k0 + 7]; if (dd < best) { best = dd; bi = k0 + 7; }
    }

    float lg[ADIM];
#pragma unroll
    for (int a = 0; a < ADIM; ++a) lg[a] = ba[a];
    float val = bv[0];
    const float4* q4 = (const float4*)(emb + (size_t)bi * HDIM);
#pragma unroll
    for (int j4 = 0; j4 < HDIM / 4; ++j4) {
        float4 q = q4[j4];
        const int j = 4 * j4;
#pragma unroll
        for (int a = 0; a < ADIM; ++a) {
            float t = lg[a];
            t = fmaf(q.x, Wa[(j + 0) * ADIM + a], t);
            t = fmaf(q.y, Wa[(j + 1) * ADIM + a], t);
            t = fmaf(q.z, Wa[(j + 2) * ADIM + a], t);
            t = fmaf(q.w, Wa[(j + 3) * ADIM + a], t);
            lg[a] = t;
        }
        val = fmaf(q.x, Wv[j + 0], val);
        val = fmaf(q.y, Wv[j + 1], val);
        val = fmaf(q.z, Wv[j + 2], val);
        val = fmaf(q.w, Wv[j + 3], val);
    }
    float m = lg[0];
#pragma unroll
    for (int a = 1; a < ADIM; ++a) m = fmaxf(m, lg[a]);
    float p[ADIM];
    float s = 0.f;
#pragma unroll
    for (int a = 0; a < ADIM; ++a) { p[a] = __expf(lg[a] - m); s += p[a]; }
    const float inv = 1.f / s;
    float4* outp = (float4*)(out + (size_t)row * ADIM);
    outp[0] = make_float4(p[0] * inv, p[1] * inv, p[2] * inv, p[3] * inv);
    outp[1] = make_float4(p[4] * inv, p[5] * inv, p[6] * inv, p[7] * inv);
    out[(size_t)NROWS * ADIM + row] = val;
}

// ===========================================================================
extern "C" void kernel_launch(void* const* d_in, const int* in_sizes, int n_in,
                              void* d_out, int out_size, void* d_ws, size_t ws_size,
                              hipStream_t stream) {
    const float* in  = (const float*)d_in[0];
    const float* W1  = (const float*)d_in[1];
    const float* b1  = (const float*)d_in[2];
    const float* Wh  = (const float*)d_in[3];
    const float* bh  = (const float*)d_in[4];
    const float* emb = (const float*)d_in[5];
    const float* Wa  = (const float*)d_in[6];
    const float* ba  = (const float*)d_in[7];
    const float* Wv  = (const float*)d_in[8];
    const float* bv  = (const float*)d_in[9];
    float* out = (float*)d_out;

    const size_t x2_f = (size_t)NROWS * HDIM;             // 64 MB
    const size_t eT_f = (size_t)KCODES * HDIM;            // 256 KB
    const size_t ee_f = KCODES;                           // 2 KB
    const size_t vv_f = NROWS;                            // 512 KB
    const size_t need = (x2_f + eT_f + ee_f + vv_f) * sizeof(float);

    if (ws_size >= need) {
        float* x2t = (float*)d_ws;
        float* eTp = x2t + x2_f;
        float* eew = eTp + eT_f;
        float* vvs = eew + ee_f;
        mlp_kernel<<<NROWS / 64, 256, 0, stream>>>(in, W1, b1, Wh, bh, x2t, vvs, NROWS,
                                                   emb, eTp, eew);
        vq_kernel<<<NROWS / 64, 256, 0, stream>>>(x2t, eTp, eew, vvs, emb,
                                                  Wa, ba, Wv, bv, out, NROWS);
    } else {
        fused_global_kernel<<<NROWS / 256, 256, 0, stream>>>(in, W1, b1, Wh, bh, emb,
                                                             Wa, ba, Wv, bv, out);
    }
}